// Round 13
// baseline (71.774 us; speedup 1.0000x reference)
//
#include <hip/hip_runtime.h>

// Problem constants (B=1): inputs (N=32768, D=1024) f32, tag_to_token (T=128, N) f32,
// gat_mask (T, T) i32. Output (T, D) f32.
#define NTOK 32768
#define NTAG 128
#define DDIM 1024
#define TPB 32  // tokens per fused block

// ws layout:
//   P   : 524288 B (unscaled per-tag sums)
//   cnt : 512 B
//   Wa  : 65536 B (128x128 matrix ping)
//   Wb  : 65536 B (128x128 matrix pong; ends as final A)

// ---------------------------------------------------------------------------
// Kernel 0 (k_prep): zero P/cnt + build the 8 group matrices (16-row
// back-substitution) into Wa. deduce_child(gm) == gm for ANY input (the
// reference inner loop is provably a no-op). Verified in R12 (absmax 0.03).
// ---------------------------------------------------------------------------
__global__ __launch_bounds__(256) void k_prep(const int* __restrict__ gm,
                                              float* __restrict__ P,
                                              int* __restrict__ cnt,
                                              float* __restrict__ Wa) {
    __shared__ float rt[16][NTAG];
    __shared__ float gblk[16][16];
    const int tid = threadIdx.x;
    const int b = blockIdx.x;

    float4* P4 = reinterpret_cast<float4*>(P);
#pragma unroll
    for (int q = 0; q < 8; ++q)
        P4[q * 4096 + b * 256 + tid] = make_float4(0.f, 0.f, 0.f, 0.f);
    if (b == 0 && tid < NTAG) cnt[tid] = 0;

    if (b >= 8) return;
    const int g0 = b * 16;
    const int t = tid & 127;

    gblk[tid >> 4][tid & 15] =
        (float)(gm[(g0 + (tid >> 4)) * NTAG + g0 + (tid & 15)] != 0);
    float grows[16];
#pragma unroll
    for (int jj = 0; jj < 16; ++jj)
        grows[jj] = (float)(gm[(g0 + jj) * NTAG + t] != 0);
    __syncthreads();

#pragma unroll
    for (int jj = 15; jj >= 0; --jj) {
        const int j = g0 + jj;
        float acc = (t > j && t < g0 + 16) ? 0.f : grows[jj];
        for (int k = jj + 1; k < 16; ++k) acc += gblk[jj][k] * rt[k][t];
        rt[jj][t] = acc;
        __syncthreads();
    }

#pragma unroll
    for (int jj = 0; jj < 16; ++jj) Wa[(g0 + jj) * NTAG + t] = rt[jj][t];
}

// ---------------------------------------------------------------------------
// One tree-combine level (same math as R12's k_comb, verified): pairs of
// adjacent S-row blocks; lo rows get the hi-span substituted, hi rows copied.
// Runs in a SINGLE block (syncthreads = level sync), Win/Wout in global (L2),
// hi rows staged per 32-col slice in 8 KB LDS.
// ---------------------------------------------------------------------------
__device__ __forceinline__ void combine_level(const float* __restrict__ Win,
                                              float* __restrict__ Wout,
                                              float* __restrict__ hi_lds,
                                              int S, int tid) {
    for (int cs = 0; cs < 128; cs += 32) {
        for (int q = tid; q < 64 * 8; q += 256) {  // stage: r = q>>3, 8 float4/row
            const int r = q >> 3;
            const int c4o = (q & 7) << 2;
            const int p = r / S, t = r % S;
            *reinterpret_cast<float4*>(&hi_lds[r * 32 + c4o]) =
                *reinterpret_cast<const float4*>(&Win[(p * 2 * S + S + t) * NTAG + cs + c4o]);
        }
        __syncthreads();
        for (int q = tid; q < 64 * 8; q += 256) {
            const int r = q >> 3;
            const int c4o = (q & 7) << 2;
            const int c4 = cs + c4o;
            const int p = r / S, rl = r % S;
            const int i = p * 2 * S + rl;
            const int hb = p * 2 * S + S;
            float4 acc = *reinterpret_cast<const float4*>(&Win[i * NTAG + c4]);
            if (c4 >= hb && c4 < hb + S) acc = make_float4(0.f, 0.f, 0.f, 0.f);
#pragma unroll 8
            for (int t = 0; t < S; ++t) {
                const float w = Win[i * NTAG + hb + t];
                const float4 h =
                    *reinterpret_cast<const float4*>(&hi_lds[(p * S + t) * 32 + c4o]);
                acc.x = fmaf(w, h.x, acc.x);
                acc.y = fmaf(w, h.y, acc.y);
                acc.z = fmaf(w, h.z, acc.z);
                acc.w = fmaf(w, h.w, acc.w);
            }
            *reinterpret_cast<float4*>(&Wout[i * NTAG + c4]) = acc;
            *reinterpret_cast<float4*>(&Wout[(hb + rl) * NTAG + c4]) =
                *reinterpret_cast<const float4*>(&hi_lds[(p * S + rl) * 32 + c4o]);
        }
        __syncthreads();
    }
}

// ---------------------------------------------------------------------------
// Kernel 1 (k_fused): blocks 0..1023 = tag-scan + segmented sum (byte-
// identical logic to R6-R12). Block 1024 = the A-builder (3 combine levels,
// Wa->Wb->Wa->Wb), which HIDES under the 1024 streaming blocks instead of
// being 3 separate small graph nodes (R12 showed small trailing nodes cost
// far more than their modeled time).
// ---------------------------------------------------------------------------
__global__ __launch_bounds__(256) void k_fused(const float* __restrict__ inp,
                                               const float* __restrict__ t2t,
                                               float* __restrict__ P,
                                               int* __restrict__ cnt,
                                               float* __restrict__ Wa,
                                               float* __restrict__ Wb) {
    __shared__ float hi_lds[64 * 32];  // 8 KB (builder block only)
    __shared__ int part[8][TPB];
    __shared__ int tags[TPB];
    const int tid = threadIdx.x;

    if (blockIdx.x == 1024) {
        combine_level(Wa, Wb, hi_lds, 16, tid);
        __syncthreads();
        combine_level(Wb, Wa, hi_lds, 32, tid);
        __syncthreads();
        combine_level(Wa, Wb, hi_lds, 64, tid);  // final A in Wb
        return;
    }

    const int n0 = blockIdx.x * TPB;
    {
        const int c = tid >> 5;
        const int n = tid & 31;
        int m = -1;
#pragma unroll
        for (int j = 0; j < 16; ++j) {
            const int r = c * 16 + j;
            if (t2t[(size_t)r * NTOK + n0 + n] > 0.f) m = r;
        }
        part[c][n] = m;
    }
    __syncthreads();
    if (tid < TPB) {
        int m = -1;
#pragma unroll
        for (int cc = 0; cc < 8; ++cc) m = max(m, part[cc][tid]);
        tags[tid] = m;
    }
    __syncthreads();

    const int col = tid * 4;
    const float4* src = reinterpret_cast<const float4*>(inp) + (size_t)n0 * 256 + tid;

    float4 acc = make_float4(0.f, 0.f, 0.f, 0.f);
    int cur = tags[0];
    int runlen = 0;

#pragma unroll
    for (int half = 0; half < 2; ++half) {
        float4 v[16];
#pragma unroll
        for (int k = 0; k < 16; ++k)
            v[k] = src[(size_t)(half * 16 + k) * 256];
#pragma unroll
        for (int k = 0; k < 16; ++k) {
            const int tg = tags[half * 16 + k];
            if (tg != cur) {
                if (cur >= 0) {
                    float* p = P + (size_t)cur * DDIM + col;
                    atomicAdd(p + 0, acc.x);
                    atomicAdd(p + 1, acc.y);
                    atomicAdd(p + 2, acc.z);
                    atomicAdd(p + 3, acc.w);
                    if (tid == 0) atomicAdd(&cnt[cur], runlen);
                }
                acc = make_float4(0.f, 0.f, 0.f, 0.f);
                cur = tg;
                runlen = 0;
            }
            if (tg >= 0) {
                acc.x += v[k].x;
                acc.y += v[k].y;
                acc.z += v[k].z;
                acc.w += v[k].w;
                ++runlen;
            }
        }
    }
    if (cur >= 0) {
        float* p = P + (size_t)cur * DDIM + col;
        atomicAdd(p + 0, acc.x);
        atomicAdd(p + 1, acc.y);
        atomicAdd(p + 2, acc.z);
        atomicAdd(p + 3, acc.w);
        if (tid == 0) atomicAdd(&cnt[cur], runlen);
    }
}

// ---------------------------------------------------------------------------
// Kernel 2 (k_applyA): out = A * (P/cnt). Verbatim from R12 (verified).
// ---------------------------------------------------------------------------
__device__ __forceinline__ void fma4(float4& a, float w, const float4& p) {
    a.x = fmaf(w, p.x, a.x);
    a.y = fmaf(w, p.y, a.y);
    a.z = fmaf(w, p.z, a.z);
    a.w = fmaf(w, p.w, a.w);
}

__global__ __launch_bounds__(256) void k_applyA(const float* __restrict__ P,
                                                const float* __restrict__ A,
                                                const int* __restrict__ cnt,
                                                float* __restrict__ out) {
    __shared__ float pl[NTAG * 32];  // 16 KB
    __shared__ float inv[NTAG];
    const int tid = threadIdx.x;
    const int c0 = blockIdx.x * 32;

    if (tid < NTAG) inv[tid] = 1.0f / (float)cnt[tid];
    __syncthreads();
    for (int q = tid; q < NTAG * 32; q += 256) {
        const int t = q >> 5, c = q & 31;
        pl[q] = P[(size_t)t * DDIM + c0 + c] * inv[t];
    }
    __syncthreads();

    const int i0 = (tid >> 3) * 4;
    const int c4 = (tid & 7) * 4;
    const float* a0 = A + (size_t)(i0 + 0) * NTAG;
    const float* a1 = A + (size_t)(i0 + 1) * NTAG;
    const float* a2 = A + (size_t)(i0 + 2) * NTAG;
    const float* a3 = A + (size_t)(i0 + 3) * NTAG;
    float4 acc0 = make_float4(0.f, 0.f, 0.f, 0.f);
    float4 acc1 = acc0, acc2 = acc0, acc3 = acc0;

#pragma unroll 8
    for (int t = 0; t < NTAG; t += 4) {
        const float4 w0 = *reinterpret_cast<const float4*>(a0 + t);
        const float4 w1 = *reinterpret_cast<const float4*>(a1 + t);
        const float4 w2 = *reinterpret_cast<const float4*>(a2 + t);
        const float4 w3 = *reinterpret_cast<const float4*>(a3 + t);
        const float4 p0 = *reinterpret_cast<const float4*>(&pl[(t + 0) * 32 + c4]);
        const float4 p1 = *reinterpret_cast<const float4*>(&pl[(t + 1) * 32 + c4]);
        const float4 p2 = *reinterpret_cast<const float4*>(&pl[(t + 2) * 32 + c4]);
        const float4 p3 = *reinterpret_cast<const float4*>(&pl[(t + 3) * 32 + c4]);
        fma4(acc0, w0.x, p0); fma4(acc0, w0.y, p1); fma4(acc0, w0.z, p2); fma4(acc0, w0.w, p3);
        fma4(acc1, w1.x, p0); fma4(acc1, w1.y, p1); fma4(acc1, w1.z, p2); fma4(acc1, w1.w, p3);
        fma4(acc2, w2.x, p0); fma4(acc2, w2.y, p1); fma4(acc2, w2.z, p2); fma4(acc2, w2.w, p3);
        fma4(acc3, w3.x, p0); fma4(acc3, w3.y, p1); fma4(acc3, w3.z, p2); fma4(acc3, w3.w, p3);
    }

    *reinterpret_cast<float4*>(out + (size_t)(i0 + 0) * DDIM + c0 + c4) = acc0;
    *reinterpret_cast<float4*>(out + (size_t)(i0 + 1) * DDIM + c0 + c4) = acc1;
    *reinterpret_cast<float4*>(out + (size_t)(i0 + 2) * DDIM + c0 + c4) = acc2;
    *reinterpret_cast<float4*>(out + (size_t)(i0 + 3) * DDIM + c0 + c4) = acc3;
}

// ---------------------------------------------------------------------------
extern "C" void kernel_launch(void* const* d_in, const int* in_sizes, int n_in,
                              void* d_out, int out_size, void* d_ws, size_t ws_size,
                              hipStream_t stream) {
    const float* inp = (const float*)d_in[0];  // (N, D)
    const float* t2t = (const float*)d_in[1];  // (T, N)
    const int* gm = (const int*)d_in[2];       // (T, T)
    float* out = (float*)d_out;                // (T, D)

    char* ws = (char*)d_ws;
    float* P = (float*)ws;                       // 524288 B
    int* cnt = (int*)(ws + 524288);              // 512 B
    float* Wa = (float*)(ws + 524800);           // 65536 B
    float* Wb = (float*)(ws + 524800 + 65536);   // 65536 B

    k_prep<<<16, 256, 0, stream>>>(gm, P, cnt, Wa);
    k_fused<<<1025, 256, 0, stream>>>(inp, t2t, P, cnt, Wa, Wb);
    k_applyA<<<32, 256, 0, stream>>>(P, Wb, cnt, out);
}

// Round 14
// 54.222 us; speedup vs baseline: 1.3237x; 1.3237x over previous
//
#include <hip/hip_runtime.h>

// Problem constants (B=1): inputs (N=32768, D=1024) f32, tag_to_token (T=128, N) f32,
// gat_mask (T, T) i32. Output (T, D) f32.
#define NTOK 32768
#define NTAG 128
#define DDIM 1024
#define TPB 32  // tokens per segsum block

// ws layout:
//   P       : 524288 B  (unscaled per-tag sums)
//   cnt     : 512 B
//   lastTag : 131072 B
//   maskT   : 2048 B    (bit-transposed gm for k_recur)

// ---------------------------------------------------------------------------
// Kernel 0 (k_zero): P=0, cnt=0, lastTag=-1; blocks 1-2 build the
// bit-transposed gm mask table as a 512-thread gather (R8, verified).
// ---------------------------------------------------------------------------
__global__ __launch_bounds__(256) void k_zero(const int* __restrict__ gm,
                                              float* __restrict__ P,
                                              int* __restrict__ cnt,
                                              int* __restrict__ lastTag,
                                              unsigned* __restrict__ maskT) {
    const int tid = threadIdx.x;
    const int gid = blockIdx.x * 256 + tid;  // 0..32767
    reinterpret_cast<float4*>(P)[gid] = make_float4(0.f, 0.f, 0.f, 0.f);
    lastTag[gid] = -1;
    if (gid < NTAG) cnt[gid] = 0;

    if (blockIdx.x == 1 || blockIdx.x == 2) {
        const int idx = (blockIdx.x - 1) * 256 + tid;  // (k*4+iw)*16+l
        const int l = idx & 15;
        const int iw = (idx >> 4) & 3;
        const int k = idx >> 6;
        const int colg = 16 * k + l;
        unsigned w = 0;
#pragma unroll
        for (int ib = 0; ib < 32; ++ib)
            w |= (unsigned)(gm[(iw * 32 + ib) * NTAG + colg] != 0) << ib;
        maskT[idx] = w;
    }
}

// ---------------------------------------------------------------------------
// Kernel 1 (k_lasttag): R4's split version (profiled ~4us there). 8 row-
// chunks x 32 token-chunks = 256 blocks; each thread partial-maxes 16 rows
// (16 independent float4 loads in flight), combines via atomicMax.
// Math fact: deduce_direct_string's temp[i][n] is 1 iff i is the LAST
// covering tag of n (for ANY 0/1 coverage), so the row-normalized t2t is
// one-hot per token / cnt[tag]. KEPT AS A SEPARATE KERNEL: R6-R13 fused this
// scan into the streaming kernel as a per-block prologue and the whole
// stream became latency-gated (~45-65us); split, both phases are fast.
// ---------------------------------------------------------------------------
__global__ __launch_bounds__(256) void k_lasttag(const float* __restrict__ t2t,
                                                 int* __restrict__ lastTag) {
    const int tokChunk = blockIdx.x & 31;
    const int rowChunk = blockIdx.x >> 5;
    const int n0 = tokChunk * 1024 + threadIdx.x * 4;
    const int j0 = rowChunk * 16;
    int l0 = -1, l1 = -1, l2 = -1, l3 = -1;
#pragma unroll
    for (int jj = 0; jj < 16; ++jj) {
        const int j = j0 + jj;
        const float4 v = *reinterpret_cast<const float4*>(t2t + (size_t)j * NTOK + n0);
        if (v.x > 0.f) l0 = j;
        if (v.y > 0.f) l1 = j;
        if (v.z > 0.f) l2 = j;
        if (v.w > 0.f) l3 = j;
    }
    if (l0 >= 0) atomicMax(&lastTag[n0 + 0], l0);
    if (l1 >= 0) atomicMax(&lastTag[n0 + 1], l1);
    if (l2 >= 0) atomicMax(&lastTag[n0 + 2], l2);
    if (l3 >= 0) atomicMax(&lastTag[n0 + 3], l3);
}

// ---------------------------------------------------------------------------
// Kernel 2 (k_segsum): pure input streaming (R4 lineage, profiled ~15us
// there). 1024 blocks x 32 tokens x 1024 cols; thread -> 4 cols (float4).
// Two halves of 16 upfront loads (16 in flight); run-length flush via
// atomicAdd into P on wave-uniform tag changes; tid 0 accumulates cnt.
// ---------------------------------------------------------------------------
__global__ __launch_bounds__(256) void k_segsum(const float* __restrict__ inp,
                                                const int* __restrict__ lastTag,
                                                float* __restrict__ P,
                                                int* __restrict__ cnt) {
    __shared__ int tags[TPB];
    const int tid = threadIdx.x;
    const int n0 = blockIdx.x * TPB;
    if (tid < TPB) tags[tid] = lastTag[n0 + tid];
    __syncthreads();

    const int col = tid * 4;
    const float4* src = reinterpret_cast<const float4*>(inp) + (size_t)n0 * 256 + tid;

    float4 acc = make_float4(0.f, 0.f, 0.f, 0.f);
    int cur = tags[0];
    int runlen = 0;

#pragma unroll
    for (int half = 0; half < 2; ++half) {
        float4 v[16];
#pragma unroll
        for (int k = 0; k < 16; ++k)
            v[k] = src[(size_t)(half * 16 + k) * 256];  // 16 loads in flight
#pragma unroll
        for (int k = 0; k < 16; ++k) {
            const int tg = tags[half * 16 + k];
            if (tg != cur) {  // wave-uniform (tags uniform across lanes)
                if (cur >= 0) {
                    float* p = P + (size_t)cur * DDIM + col;
                    atomicAdd(p + 0, acc.x);
                    atomicAdd(p + 1, acc.y);
                    atomicAdd(p + 2, acc.z);
                    atomicAdd(p + 3, acc.w);
                    if (tid == 0) atomicAdd(&cnt[cur], runlen);
                }
                acc = make_float4(0.f, 0.f, 0.f, 0.f);
                cur = tg;
                runlen = 0;
            }
            if (tg >= 0) {
                acc.x += v[k].x;
                acc.y += v[k].y;
                acc.z += v[k].z;
                acc.w += v[k].w;
                ++runlen;
            }
        }
    }
    if (cur >= 0) {
        float* p = P + (size_t)cur * DDIM + col;
        atomicAdd(p + 0, acc.x);
        atomicAdd(p + 1, acc.y);
        atomicAdd(p + 2, acc.z);
        atomicAdd(p + 3, acc.w);
        if (tid == 0) atomicAdd(&cnt[cur], runlen);
    }
}

// ---------------------------------------------------------------------------
// Kernel 3 (k_recur): R8's all-register DPP recurrence, verbatim (verified;
// under the corrected ledger it was already ~5us). deduce_child(gm) == gm
// for ANY input. One wave = 4 columns (16-lane groups); o in 8 VGPRs; gm
// bits in 32 VGPRs from maskT; per step: 8x shift/and/cvt/fmac + 4 DPP adds
// + 1 guarded move; ~6KB body; no memory in the loop.
// ---------------------------------------------------------------------------
template <int CTRL>
__device__ __forceinline__ float dpp_add(float x) {
    const int y = __builtin_amdgcn_update_dpp(0, __float_as_int(x), CTRL, 0xF, 0xF, true);
    return x + __int_as_float(y);
}

__global__ __launch_bounds__(64, 1) void k_recur(const float* __restrict__ P,
                                                 const unsigned* __restrict__ maskT,
                                                 const int* __restrict__ cnt,
                                                 float* __restrict__ out) {
    __shared__ float xpose[NTAG][5];
    const int L = threadIdx.x;
    const int g = L >> 4;
    const int l = L & 15;
    const int c0 = blockIdx.x * 4;

    unsigned mw[8][4];
#pragma unroll
    for (int k = 0; k < 8; ++k)
#pragma unroll
        for (int iw = 0; iw < 4; ++iw) mw[k][iw] = maskT[(k * 4 + iw) * 16 + l];

    const float ia = 1.0f / (float)cnt[L];
    const float ib_ = 1.0f / (float)cnt[64 + L];
    float4 pa = *reinterpret_cast<const float4*>(P + (size_t)L * DDIM + c0);
    float4 pb = *reinterpret_cast<const float4*>(P + (size_t)(64 + L) * DDIM + c0);
    xpose[L][0] = pa.x * ia;
    xpose[L][1] = pa.y * ia;
    xpose[L][2] = pa.z * ia;
    xpose[L][3] = pa.w * ia;
    xpose[64 + L][0] = pb.x * ib_;
    xpose[64 + L][1] = pb.y * ib_;
    xpose[64 + L][2] = pb.z * ib_;
    xpose[64 + L][3] = pb.w * ib_;
    __syncthreads();

    float o0 = xpose[l][g], o1 = xpose[16 + l][g];
    float o2 = xpose[32 + l][g], o3 = xpose[48 + l][g];
    float o4 = xpose[64 + l][g], o5 = xpose[80 + l][g];
    float o6 = xpose[96 + l][g], o7 = xpose[112 + l][g];

#define SECTION(IW, KU, IBHI, IBLO)                                         \
    _Pragma("unroll 2") for (int ib = IBHI; ib >= IBLO; --ib) {             \
        float sa = (float)((mw[0][IW] >> ib) & 1u) * o0;                    \
        sa += (float)((mw[1][IW] >> ib) & 1u) * o1;                         \
        sa += (float)((mw[2][IW] >> ib) & 1u) * o2;                         \
        sa += (float)((mw[3][IW] >> ib) & 1u) * o3;                         \
        float sb = (float)((mw[4][IW] >> ib) & 1u) * o4;                    \
        sb += (float)((mw[5][IW] >> ib) & 1u) * o5;                         \
        sb += (float)((mw[6][IW] >> ib) & 1u) * o6;                         \
        sb += (float)((mw[7][IW] >> ib) & 1u) * o7;                         \
        float s = sa + sb;                                                  \
        s = dpp_add<0xB1>(s);                                               \
        s = dpp_add<0x4E>(s);                                               \
        s = dpp_add<0x141>(s);                                              \
        s = dpp_add<0x140>(s);                                              \
        if (l == (ib & 15)) o##KU = s;                                      \
    }

    SECTION(3, 7, 31, 16)
    SECTION(3, 6, 15, 0)
    SECTION(2, 5, 31, 16)
    SECTION(2, 4, 15, 0)
    SECTION(1, 3, 31, 16)
    SECTION(1, 2, 15, 0)
    SECTION(0, 1, 31, 16)
    SECTION(0, 0, 15, 0)
#undef SECTION

    __syncthreads();
    xpose[l][g] = o0;
    xpose[16 + l][g] = o1;
    xpose[32 + l][g] = o2;
    xpose[48 + l][g] = o3;
    xpose[64 + l][g] = o4;
    xpose[80 + l][g] = o5;
    xpose[96 + l][g] = o6;
    xpose[112 + l][g] = o7;
    __syncthreads();
    float4 ra, rb;
    ra.x = xpose[L][0];
    ra.y = xpose[L][1];
    ra.z = xpose[L][2];
    ra.w = xpose[L][3];
    rb.x = xpose[64 + L][0];
    rb.y = xpose[64 + L][1];
    rb.z = xpose[64 + L][2];
    rb.w = xpose[64 + L][3];
    *reinterpret_cast<float4*>(out + (size_t)L * DDIM + c0) = ra;
    *reinterpret_cast<float4*>(out + (size_t)(64 + L) * DDIM + c0) = rb;
}

// ---------------------------------------------------------------------------
extern "C" void kernel_launch(void* const* d_in, const int* in_sizes, int n_in,
                              void* d_out, int out_size, void* d_ws, size_t ws_size,
                              hipStream_t stream) {
    const float* inp = (const float*)d_in[0];  // (N, D)
    const float* t2t = (const float*)d_in[1];  // (T, N)
    const int* gm = (const int*)d_in[2];       // (T, T)
    float* out = (float*)d_out;                // (T, D)

    char* ws = (char*)d_ws;
    float* P = (float*)ws;                        // 524288 B
    int* cnt = (int*)(ws + 524288);               // 512 B
    int* lastTag = (int*)(ws + 524800);           // 131072 B
    unsigned* maskT = (unsigned*)(ws + 655872);   // 2048 B

    k_zero<<<128, 256, 0, stream>>>(gm, P, cnt, lastTag, maskT);
    k_lasttag<<<256, 256, 0, stream>>>(t2t, lastTag);
    k_segsum<<<NTOK / TPB, 256, 0, stream>>>(inp, lastTag, P, cnt);
    k_recur<<<DDIM / 4, 64, 0, stream>>>(P, maskT, cnt, out);
}

// Round 15
// 51.122 us; speedup vs baseline: 1.4040x; 1.0606x over previous
//
#include <hip/hip_runtime.h>

// Problem constants (B=1): inputs (N=32768, D=1024) f32, tag_to_token (T=128, N) f32,
// gat_mask (T, T) i32. Output (T, D) f32.
#define NTOK 32768
#define NTAG 128
#define DDIM 1024
#define TPB 32  // tokens per fused block

// ws layout:
//   P     : 524288 B (unscaled per-tag sums)
//   cnt   : 512 B
//   maskT : 2048 B   (bit-transposed gm for k_recur)

// ---------------------------------------------------------------------------
// Kernel 0 (k_zero): zero P/cnt; blocks 1-2 build the bit-transposed gm mask
// table as a 512-thread gather (verified R8-R14).
// ---------------------------------------------------------------------------
__global__ __launch_bounds__(256) void k_zero(const int* __restrict__ gm,
                                              float* __restrict__ P,
                                              int* __restrict__ cnt,
                                              unsigned* __restrict__ maskT) {
    const int tid = threadIdx.x;
    const int gid = blockIdx.x * 256 + tid;
    reinterpret_cast<float4*>(P)[gid] = make_float4(0.f, 0.f, 0.f, 0.f);
    if (gid < NTAG) cnt[gid] = 0;

    if (blockIdx.x == 1 || blockIdx.x == 2) {
        const int idx = (blockIdx.x - 1) * 256 + tid;  // (k*4+iw)*16+l
        const int l = idx & 15;
        const int iw = (idx >> 4) & 3;
        const int k = idx >> 6;
        const int colg = 16 * k + l;
        unsigned w = 0;
#pragma unroll
        for (int ib = 0; ib < 32; ++ib)
            w |= (unsigned)(gm[(iw * 32 + ib) * NTAG + colg] != 0) << ib;
        maskT[idx] = w;
    }
}

// ---------------------------------------------------------------------------
// Kernel 1 (k_fused): tag-scan + segmented sum, R8-verbatim EXCEPT
// __launch_bounds__(256, 1).
//
// ROUND 15 FIX: R13's profile showed this kernel at VGPR_Count=40 — but
// float4 v[16] alone needs 64 VGPRs. The default occupancy heuristic rolled
// the 16 upfront loads into a ~4-deep load->use window -> latency-bound at
// ~1.7 TB/s effective (VALUBusy 3.5%, Occ 21%, both-low signature). The
// min-waves=1 bound lifts the VGPR budget so all 16 loads per half are
// genuinely in flight; ~90 VGPR still leaves ~16 waves/CU of TLP.
//
// Math fact: deduce_direct_string's temp[i][n] is 1 iff i is the LAST
// covering tag of n (for ANY 0/1 coverage), so the row-normalized t2t is
// one-hot per token / cnt[tag] -> the big matmul is a segmented sum into
// P[tag], scaled later by 1/cnt.
// ---------------------------------------------------------------------------
__global__ __launch_bounds__(256, 1) void k_fused(const float* __restrict__ inp,
                                                  const float* __restrict__ t2t,
                                                  float* __restrict__ P,
                                                  int* __restrict__ cnt) {
    __shared__ int part[8][TPB];
    __shared__ int tags[TPB];
    const int tid = threadIdx.x;
    const int n0 = blockIdx.x * TPB;

    // ---- Phase 1: tags for this block's 32 tokens ----
    {
        const int c = tid >> 5;  // row chunk (16 rows)
        const int n = tid & 31;  // token within block
        int m = -1;
#pragma unroll
        for (int j = 0; j < 16; ++j) {
            const int r = c * 16 + j;
            if (t2t[(size_t)r * NTOK + n0 + n] > 0.f) m = r;
        }
        part[c][n] = m;
    }
    __syncthreads();
    if (tid < TPB) {
        int m = -1;
#pragma unroll
        for (int cc = 0; cc < 8; ++cc) m = max(m, part[cc][tid]);
        tags[tid] = m;
    }
    __syncthreads();

    // ---- Phase 2: stream 32 input rows, run-length flush ----
    const int col = tid * 4;
    const float4* src = reinterpret_cast<const float4*>(inp) + (size_t)n0 * 256 + tid;

    float4 acc = make_float4(0.f, 0.f, 0.f, 0.f);
    int cur = tags[0];
    int runlen = 0;

#pragma unroll
    for (int half = 0; half < 2; ++half) {
        float4 v[16];
#pragma unroll
        for (int k = 0; k < 16; ++k)
            v[k] = src[(size_t)(half * 16 + k) * 256];  // 16 loads in flight
#pragma unroll
        for (int k = 0; k < 16; ++k) {
            const int tg = tags[half * 16 + k];
            if (tg != cur) {  // wave-uniform (tags uniform across lanes)
                if (cur >= 0) {
                    float* p = P + (size_t)cur * DDIM + col;
                    atomicAdd(p + 0, acc.x);
                    atomicAdd(p + 1, acc.y);
                    atomicAdd(p + 2, acc.z);
                    atomicAdd(p + 3, acc.w);
                    if (tid == 0) atomicAdd(&cnt[cur], runlen);
                }
                acc = make_float4(0.f, 0.f, 0.f, 0.f);
                cur = tg;
                runlen = 0;
            }
            if (tg >= 0) {
                acc.x += v[k].x;
                acc.y += v[k].y;
                acc.z += v[k].z;
                acc.w += v[k].w;
                ++runlen;
            }
        }
    }
    if (cur >= 0) {
        float* p = P + (size_t)cur * DDIM + col;
        atomicAdd(p + 0, acc.x);
        atomicAdd(p + 1, acc.y);
        atomicAdd(p + 2, acc.z);
        atomicAdd(p + 3, acc.w);
        if (tid == 0) atomicAdd(&cnt[cur], runlen);
    }
}

// ---------------------------------------------------------------------------
// Kernel 2 (k_recur): all-register DPP recurrence (verified R8-R14).
// deduce_child(gm) == gm for ANY input (reference inner loop provably a
// no-op). One wave = 4 columns (16-lane groups); o in 8 VGPRs; gm bits in
// 32 VGPRs from maskT; per step: 8x shift/and/cvt/fmac + 4 DPP adds + 1
// guarded move; no memory in the loop; ~6KB body.
// ---------------------------------------------------------------------------
template <int CTRL>
__device__ __forceinline__ float dpp_add(float x) {
    const int y = __builtin_amdgcn_update_dpp(0, __float_as_int(x), CTRL, 0xF, 0xF, true);
    return x + __int_as_float(y);
}

__global__ __launch_bounds__(64, 1) void k_recur(const float* __restrict__ P,
                                                 const unsigned* __restrict__ maskT,
                                                 const int* __restrict__ cnt,
                                                 float* __restrict__ out) {
    __shared__ float xpose[NTAG][5];
    const int L = threadIdx.x;
    const int g = L >> 4;
    const int l = L & 15;
    const int c0 = blockIdx.x * 4;

    unsigned mw[8][4];
#pragma unroll
    for (int k = 0; k < 8; ++k)
#pragma unroll
        for (int iw = 0; iw < 4; ++iw) mw[k][iw] = maskT[(k * 4 + iw) * 16 + l];

    const float ia = 1.0f / (float)cnt[L];
    const float ib_ = 1.0f / (float)cnt[64 + L];
    float4 pa = *reinterpret_cast<const float4*>(P + (size_t)L * DDIM + c0);
    float4 pb = *reinterpret_cast<const float4*>(P + (size_t)(64 + L) * DDIM + c0);
    xpose[L][0] = pa.x * ia;
    xpose[L][1] = pa.y * ia;
    xpose[L][2] = pa.z * ia;
    xpose[L][3] = pa.w * ia;
    xpose[64 + L][0] = pb.x * ib_;
    xpose[64 + L][1] = pb.y * ib_;
    xpose[64 + L][2] = pb.z * ib_;
    xpose[64 + L][3] = pb.w * ib_;
    __syncthreads();

    float o0 = xpose[l][g], o1 = xpose[16 + l][g];
    float o2 = xpose[32 + l][g], o3 = xpose[48 + l][g];
    float o4 = xpose[64 + l][g], o5 = xpose[80 + l][g];
    float o6 = xpose[96 + l][g], o7 = xpose[112 + l][g];

#define SECTION(IW, KU, IBHI, IBLO)                                         \
    _Pragma("unroll 2") for (int ib = IBHI; ib >= IBLO; --ib) {             \
        float sa = (float)((mw[0][IW] >> ib) & 1u) * o0;                    \
        sa += (float)((mw[1][IW] >> ib) & 1u) * o1;                         \
        sa += (float)((mw[2][IW] >> ib) & 1u) * o2;                         \
        sa += (float)((mw[3][IW] >> ib) & 1u) * o3;                         \
        float sb = (float)((mw[4][IW] >> ib) & 1u) * o4;                    \
        sb += (float)((mw[5][IW] >> ib) & 1u) * o5;                         \
        sb += (float)((mw[6][IW] >> ib) & 1u) * o6;                         \
        sb += (float)((mw[7][IW] >> ib) & 1u) * o7;                         \
        float s = sa + sb;                                                  \
        s = dpp_add<0xB1>(s);                                               \
        s = dpp_add<0x4E>(s);                                               \
        s = dpp_add<0x141>(s);                                              \
        s = dpp_add<0x140>(s);                                              \
        if (l == (ib & 15)) o##KU = s;                                      \
    }

    SECTION(3, 7, 31, 16)
    SECTION(3, 6, 15, 0)
    SECTION(2, 5, 31, 16)
    SECTION(2, 4, 15, 0)
    SECTION(1, 3, 31, 16)
    SECTION(1, 2, 15, 0)
    SECTION(0, 1, 31, 16)
    SECTION(0, 0, 15, 0)
#undef SECTION

    __syncthreads();
    xpose[l][g] = o0;
    xpose[16 + l][g] = o1;
    xpose[32 + l][g] = o2;
    xpose[48 + l][g] = o3;
    xpose[64 + l][g] = o4;
    xpose[80 + l][g] = o5;
    xpose[96 + l][g] = o6;
    xpose[112 + l][g] = o7;
    __syncthreads();
    float4 ra, rb;
    ra.x = xpose[L][0];
    ra.y = xpose[L][1];
    ra.z = xpose[L][2];
    ra.w = xpose[L][3];
    rb.x = xpose[64 + L][0];
    rb.y = xpose[64 + L][1];
    rb.z = xpose[64 + L][2];
    rb.w = xpose[64 + L][3];
    *reinterpret_cast<float4*>(out + (size_t)L * DDIM + c0) = ra;
    *reinterpret_cast<float4*>(out + (size_t)(64 + L) * DDIM + c0) = rb;
}

// ---------------------------------------------------------------------------
extern "C" void kernel_launch(void* const* d_in, const int* in_sizes, int n_in,
                              void* d_out, int out_size, void* d_ws, size_t ws_size,
                              hipStream_t stream) {
    const float* inp = (const float*)d_in[0];  // (N, D)
    const float* t2t = (const float*)d_in[1];  // (T, N)
    const int* gm = (const int*)d_in[2];       // (T, T)
    float* out = (float*)d_out;                // (T, D)

    char* ws = (char*)d_ws;
    float* P = (float*)ws;                       // 524288 B
    int* cnt = (int*)(ws + 524288);              // 512 B
    unsigned* maskT = (unsigned*)(ws + 524800);  // 2048 B

    k_zero<<<128, 256, 0, stream>>>(gm, P, cnt, maskT);
    k_fused<<<NTOK / TPB, 256, 0, stream>>>(inp, t2t, P, cnt);
    k_recur<<<DDIM / 4, 64, 0, stream>>>(P, maskT, cnt, out);
}